// Round 3
// baseline (198.592 us; speedup 1.0000x reference)
//
#include <hip/hip_runtime.h>
#include <math.h>

// Weights / constants from the reference
#define INSIDE_W   0.5f
#define OUTSIDE_W  2.0f
#define CONTACT_W  0.5f
#define HCP_W      1.0f
#define POSE_W     0.01f
#define HANDPOSE_W 0.01f
#define ANGLE_W    0.1f
#define A1c 0.04f
#define A2c 0.04f
#define B1c 0.07f
#define B2c 0.06f
#define C1c 0.01f
#define C2c 0.01f
#define D1c 0.023f
#define D2c 0.02f

#define FBIG 3.402823e38f

typedef float f32x4 __attribute__((ext_vector_type(4)));

__device__ __forceinline__ float waveReduceSum(float x) {
#pragma unroll
    for (int o = 32; o > 0; o >>= 1) x += __shfl_down(x, o, 64);
    return x;
}
__device__ __forceinline__ float waveReduceMin(float x) {
#pragma unroll
    for (int o = 32; o > 0; o >>= 1) x = fminf(x, __shfl_down(x, o, 64));
    return x;
}

// Accumulator slots in ws (floats):
// 0: outside_sum
// 1: contact_sum  2: contact_cnt
// 3: inside_sum   4: inside_cnt
// 5: lout_sum     6: lout_cnt
// 7: rout_sum     8: rout_cnt
// 9: lin_sum     10: lin_cnt
// 11: rin_sum    12: rin_cnt
// 13: ag_sum     14: close_cnt
// 15,16,17: nbar_sum xyz

// Init 4 shifted mask copies to +FBIG and gdi to +FBIG.
__global__ __launch_bounds__(256) void k_init(
    float* __restrict__ big4, int nbig, float* __restrict__ gdi, int NV)
{
    int t = blockIdx.x * blockDim.x + threadIdx.x;
    if (t < nbig) big4[t] = FBIG;
    if (t < NV)   gdi[t]  = FBIG;
}

// Scatter -FBIG at contact columns into all 4 shifted copies.
// Copy p holds big[j+p] at index j, so column c lands at index c-p.
__global__ __launch_bounds__(256) void k_scatter_big4(
    float* __restrict__ big4, const int* __restrict__ ivc, int NC, int NVPAD)
{
    int j = blockIdx.x * blockDim.x + threadIdx.x;
    if (j < NC) {
        int c = ivc[j];
#pragma unroll
        for (int p = 0; p < 4; ++p) {
            if (c >= p) big4[(size_t)p * NVPAD + (c - p)] = -FBIG;
        }
    }
}

// K1: flat linear sweep over the whole geodist matrix in storage order
// (m13-style single contiguous window). Per float4: masked-min with the
// L2-resident shifted mask; wave-segmented reduce (span <= 2 rows);
// integer atomicMin on float bits (all values positive).
__global__ __launch_bounds__(256) void k_gdi_flat(
    const float* __restrict__ geodist, const float* __restrict__ big4,
    float* __restrict__ gdi, unsigned NV, unsigned NVPAD, unsigned NQ)
{
    unsigned gid = blockIdx.x * blockDim.x + threadIdx.x;
    unsigned gs  = gridDim.x * blockDim.x;
    int lane = threadIdx.x & 63;

    for (unsigned q = gid; q < NQ; q += gs) {
        unsigned e = q << 2;
        unsigned r = e / NV;
        unsigned c = e - r * NV;
        f32x4 val = *(const f32x4*)(geodist + e);
        float m  = FBIG;   // min for row r
        float mB = FBIG;   // min for row r+1 (wrap lane only)
        bool wrap = (c + 3u >= NV);
        if (!wrap) {
            unsigned p = c & 3u;
            const f32x4 bg = *(const f32x4*)(big4 + (size_t)p * NVPAD + (c - p));
            float m0 = fminf(fmaxf(val[0], bg[0]), fmaxf(val[1], bg[1]));
            float m1 = fminf(fmaxf(val[2], bg[2]), fmaxf(val[3], bg[3]));
            m = fminf(m0, m1);
        } else {
#pragma unroll
            for (int k = 0; k < 4; ++k) {
                unsigned ck = c + k;
                float mm;
                if (ck >= NV) { ck -= NV; mm = fmaxf(val[k], big4[ck]); mB = fminf(mB, mm); }
                else          { mm = fmaxf(val[k], big4[ck]); m = fminf(m, mm); }
            }
        }
        // wave covers 256 consecutive elements -> at most 2 rows
        unsigned rA = (unsigned)__shfl((int)r, 0, 64);
        unsigned rL = (unsigned)__shfl((int)r, 63, 64);
        int wrapL   = __shfl((int)wrap, 63, 64);
        unsigned rB = rL + (wrapL ? 1u : 0u);
        if (rA == rB) {
            float mm = waveReduceMin(m);
            if (lane == 0 && mm < FBIG)
                atomicMin((int*)&gdi[rA], __float_as_int(mm));
        } else {
            float mlo = (r == rA) ? m : FBIG;
            float mhi = (r == rB) ? m : mB;
            mlo = waveReduceMin(mlo);
            mhi = waveReduceMin(mhi);
            if (lane == 0) {
                if (mlo < FBIG) atomicMin((int*)&gdi[rA], __float_as_int(mlo));
                if (mhi < FBIG) atomicMin((int*)&gdi[rB], __float_as_int(mhi));
            }
        }
    }
    // tail (NV*NV not divisible by 4)
    if (gid == 0) {
        unsigned NE = NV * NV;
        for (unsigned e = NQ << 2; e < NE; ++e) {
            unsigned r = e / NV;
            unsigned c = e - r * NV;
            float mm = fmaxf(geodist[e], big4[c]);
            if (mm < FBIG) atomicMin((int*)&gdi[r], __float_as_int(mm));
        }
    }
}

// K2: face normals scatter-add + inside[] scatter.
__global__ __launch_bounds__(256) void k_faces(
    const float* __restrict__ verts, const int* __restrict__ faces,
    float* __restrict__ vn, const int* __restrict__ ds,
    const int* __restrict__ exterior, int* __restrict__ inside,
    int NF, int NDS)
{
    int t = blockIdx.x * blockDim.x + threadIdx.x;
    if (t < NF) {
        int i0 = faces[t * 3 + 0];
        int i1 = faces[t * 3 + 1];
        int i2 = faces[t * 3 + 2];
        float p0x = verts[i0 * 3 + 0], p0y = verts[i0 * 3 + 1], p0z = verts[i0 * 3 + 2];
        float ax = verts[i1 * 3 + 0] - p0x;
        float ay = verts[i1 * 3 + 1] - p0y;
        float az = verts[i1 * 3 + 2] - p0z;
        float bx = verts[i2 * 3 + 0] - p0x;
        float by = verts[i2 * 3 + 1] - p0y;
        float bz = verts[i2 * 3 + 2] - p0z;
        float nx = ay * bz - az * by;
        float ny = az * bx - ax * bz;
        float nz = ax * by - ay * bx;
        atomicAdd(&vn[i0 * 3 + 0], nx);
        atomicAdd(&vn[i0 * 3 + 1], ny);
        atomicAdd(&vn[i0 * 3 + 2], nz);
        atomicAdd(&vn[i1 * 3 + 0], nx);
        atomicAdd(&vn[i1 * 3 + 1], ny);
        atomicAdd(&vn[i1 * 3 + 2], nz);
        atomicAdd(&vn[i2 * 3 + 0], nx);
        atomicAdd(&vn[i2 * 3 + 1], ny);
        atomicAdd(&vn[i2 * 3 + 2], nz);
    }
    if (t < NDS) {
        inside[ds[t]] = exterior[t] ? 0 : 1;
    }
}

// K3: normalize vn in place; accumulate nbar sums.
__global__ __launch_bounds__(256) void k_normalize(
    float* __restrict__ vn, float* __restrict__ accum, int NV)
{
    int t = blockIdx.x * blockDim.x + threadIdx.x;
    float x = 0.f, y = 0.f, z = 0.f;
    if (t < NV) {
        x = vn[t * 3 + 0];
        y = vn[t * 3 + 1];
        z = vn[t * 3 + 2];
        float inv = 1.0f / (sqrtf(x * x + y * y + z * z) + 1e-12f);
        x *= inv; y *= inv; z *= inv;
        vn[t * 3 + 0] = x;
        vn[t * 3 + 1] = y;
        vn[t * 3 + 2] = z;
    }
    x = waveReduceSum(x);
    y = waveReduceSum(y);
    z = waveReduceSum(z);
    __shared__ float s[4][3];
    int lane = threadIdx.x & 63;
    int w = threadIdx.x >> 6;
    if (lane == 0) { s[w][0] = x; s[w][1] = y; s[w][2] = z; }
    __syncthreads();
    if (threadIdx.x < 3) {
        float v = s[0][threadIdx.x] + s[1][threadIdx.x] + s[2][threadIdx.x] + s[3][threadIdx.x];
        atomicAdd(&accum[15 + threadIdx.x], v);
    }
}

// K4: contact / inside / hand / angle / outside masked sums.
__global__ __launch_bounds__(256) void k_terms(
    const float* __restrict__ v2v_min, const int* __restrict__ v2v_min_idx,
    const float* __restrict__ vn, const float* __restrict__ gdi,
    const int* __restrict__ ds, const int* __restrict__ exterior,
    const int* __restrict__ hcp, const float* __restrict__ hcpw,
    const int* __restrict__ inside,
    const float* __restrict__ verts, const float* __restrict__ iverts,
    float* __restrict__ accum, int NV, int NDS, int HA)
{
    int t = blockIdx.x * blockDim.x + threadIdx.x;
    float acc[15];
#pragma unroll
    for (int k = 0; k < 15; ++k) acc[k] = 0.f;
    // angle + outside terms (per vertex)
    if (t < NV) {
        float vm = v2v_min[t];
        if (vm < 0.01f) {
            int idx = v2v_min_idx[t];
            float nbx = accum[15] / (float)NV;
            float nby = accum[16] / (float)NV;
            float nbz = accum[17] / (float)NV;
            float d = vn[idx * 3 + 0] * nbx + vn[idx * 3 + 1] * nby + vn[idx * 3 + 2] * nbz;
            acc[13] += 1.0f + d;  // ag_sum
            acc[14] += 1.0f;      // close_cnt
        }
        float g = gdi[t];
        float dx = iverts[t * 3 + 0] - verts[t * 3 + 0];
        float dy = iverts[t * 3 + 1] - verts[t * 3 + 1];
        float dz = iverts[t * 3 + 2] - verts[t * 3 + 2];
        float v2v0 = sqrtf(dx * dx + dy * dy + dz * dz);
        float w0 = 2.0f * g;
        acc[0] += v2v0 * w0 * w0;  // outside_sum
    }
    // contact / inside terms over ds
    if (t < NDS) {
        int d = ds[t];
        int ext = exterior[t];
        float vm = v2v_min[d];
        if (ext) {
            float g = gdi[d];
            float wo = 1.0f / (5.0f * g + 1.0f);
            acc[1] += A1c * wo * tanhf(vm / A2c);  // contact_sum
            acc[2] += 1.0f;
        } else {
            acc[3] += B1c * tanhf(vm / B2c);       // inside_sum
            acc[4] += 1.0f;
        }
    }
    // hand contact terms
    if (t < HA) {
        int li = hcp[t];
        int ri = hcp[HA + t];
        float lw = 1.0f - 0.1f * hcpw[t];
        float rw = 1.0f - 0.1f * hcpw[HA + t];
        float lvm = v2v_min[li];
        float rvm = v2v_min[ri];
        if (inside[li]) {
            acc[9]  += D1c * tanhf(lvm / D2c);     // lin_sum
            acc[10] += 1.0f;
        } else {
            acc[5] += lw * C1c * tanhf(lvm / C2c); // lout_sum
            acc[6] += 1.0f;
        }
        if (inside[ri]) {
            acc[11] += D1c * tanhf(rvm / D2c);     // rin_sum
            acc[12] += 1.0f;
        } else {
            acc[7] += rw * C1c * tanhf(rvm / C2c); // rout_sum
            acc[8] += 1.0f;
        }
    }
#pragma unroll
    for (int k = 0; k < 15; ++k) acc[k] = waveReduceSum(acc[k]);
    __shared__ float s[4][15];
    int lane = threadIdx.x & 63;
    int w = threadIdx.x >> 6;
    if (lane == 0) {
#pragma unroll
        for (int k = 0; k < 15; ++k) s[w][k] = acc[k];
    }
    __syncthreads();
    if (threadIdx.x < 15) {
        float v = s[0][threadIdx.x] + s[1][threadIdx.x] + s[2][threadIdx.x] + s[3][threadIdx.x];
        atomicAdd(&accum[threadIdx.x], v);
    }
}

// K5: pose sums + final combine.
__global__ __launch_bounds__(128) void k_final(
    const float* __restrict__ accum,
    const float* __restrict__ bp, const float* __restrict__ ip,
    const float* __restrict__ lh, const float* __restrict__ rh,
    float* __restrict__ out)
{
    int t = threadIdx.x;
    float pose = 0.f, hand = 0.f;
    if (t < 63) {
        float d = bp[t] - ip[t];
        pose = d * d;
    }
    if (t < 45) {
        hand = lh[t] * lh[t] + rh[t] * rh[t];
    }
    pose = waveReduceSum(pose);
    hand = waveReduceSum(hand);
    __shared__ float s[2][2];
    int lane = t & 63;
    int w = t >> 6;
    if (lane == 0) { s[w][0] = pose; s[w][1] = hand; }
    __syncthreads();
    if (t == 0) {
        pose = s[0][0] + s[1][0];
        hand = s[0][1] + s[1][1];
        float contact_s = accum[1], contact_c = accum[2];
        float inside_s = accum[3], inside_c = accum[4];
        float lout_s = accum[5], lout_c = accum[6];
        float rout_s = accum[7], rout_c = accum[8];
        float lin_s = accum[9], lin_c = accum[10];
        float rin_s = accum[11], rin_c = accum[12];
        float ag_s = accum[13], close_c = accum[14];
        float contactloss = CONTACT_W * (contact_c > 0.f ? contact_s / contact_c : 0.f);
        float insideloss = INSIDE_W * (inside_c > 0.f ? inside_s / inside_c : 0.f);
        float hc_out = (lout_c > 0.f ? lout_s / lout_c : 0.f) + (rout_c > 0.f ? rout_s / rout_c : 0.f);
        float hc_in = (lin_c > 0.f ? lin_s / lin_c : 0.f) + (rin_c > 0.f ? rin_s / rin_c : 0.f);
        float hand_contact_loss = HCP_W * (hc_in + hc_out);
        float angle_loss = ANGLE_W * (close_c > 0.f ? ag_s / close_c : 0.f);
        float outsideloss = OUTSIDE_W * accum[0];
        float pose_prior_loss = POSE_W * pose;
        float hand_pose_prior_loss = HANDPOSE_W * hand;
        out[0] = contactloss + insideloss + outsideloss + pose_prior_loss +
                 hand_pose_prior_loss + angle_loss + hand_contact_loss;
    }
}

extern "C" void kernel_launch(void* const* d_in, const int* in_sizes, int n_in,
                              void* d_out, int out_size, void* d_ws, size_t ws_size,
                              hipStream_t stream)
{
    const float* verts    = (const float*)d_in[0];
    const float* v2v_min  = (const float*)d_in[1];
    const float* geodist  = (const float*)d_in[2];
    const float* hcpw     = (const float*)d_in[3];
    const float* bp       = (const float*)d_in[4];
    const float* ip       = (const float*)d_in[5];
    const float* lh       = (const float*)d_in[6];
    const float* rh       = (const float*)d_in[7];
    const float* iverts   = (const float*)d_in[8];
    const int*   vmi      = (const int*)d_in[9];
    const int*   exterior = (const int*)d_in[10];
    const int*   ds       = (const int*)d_in[11];
    const int*   ivc      = (const int*)d_in[12];
    const int*   hcp      = (const int*)d_in[13];
    const int*   faces    = (const int*)d_in[14];

    int NV  = in_sizes[1];
    int NDS = in_sizes[11];
    int NC  = in_sizes[12];
    int HA  = in_sizes[13] / 2;
    int NF  = in_sizes[14] / 3;

    int NVPAD = (NV + 15) & ~15;   // multiple of 16, keeps each shift-copy 16B aligned

    float* accum  = (float*)d_ws;                 // 32 floats
    float* vn     = accum + 32;                   // 3*NV floats
    int*   inside = (int*)(vn + 3 * (size_t)NV);  // NV ints
    float* gdi    = (float*)(inside + NV);        // NV floats
    size_t off = 32 + 5 * (size_t)NV;
    off = (off + 3) & ~(size_t)3;                 // 16B-align big4
    float* big4   = (float*)d_ws + off;           // 4 * NVPAD floats

    size_t zbytes = (size_t)(32 + 4 * (size_t)NV) * sizeof(float); // accum+vn+inside
    hipMemsetAsync(d_ws, 0, zbytes, stream);

    int nbig = 4 * NVPAD;
    k_init<<<(nbig + 255) / 256, 256, 0, stream>>>(big4, nbig, gdi, NV);
    k_scatter_big4<<<(NC + 255) / 256, 256, 0, stream>>>(big4, ivc, NC, NVPAD);

    unsigned NE = (unsigned)NV * (unsigned)NV;
    unsigned NQ = NE >> 2;
    k_gdi_flat<<<2048, 256, 0, stream>>>(geodist, big4, gdi,
                                         (unsigned)NV, (unsigned)NVPAD, NQ);

    int nmax = (NF > NDS) ? NF : NDS;
    k_faces<<<(nmax + 255) / 256, 256, 0, stream>>>(verts, faces, vn, ds, exterior, inside, NF, NDS);

    k_normalize<<<(NV + 255) / 256, 256, 0, stream>>>(vn, accum, NV);

    k_terms<<<(NV + 255) / 256, 256, 0, stream>>>(v2v_min, vmi, vn, gdi, ds, exterior,
                                                  hcp, hcpw, inside, verts, iverts,
                                                  accum, NV, NDS, HA);

    k_final<<<1, 128, 0, stream>>>(accum, bp, ip, lh, rh, (float*)d_out);
}

// Round 4
// 104.308 us; speedup vs baseline: 1.9039x; 1.9039x over previous
//
#include <hip/hip_runtime.h>
#include <math.h>

// Weights / constants from the reference
#define INSIDE_W   0.5f
#define OUTSIDE_W  2.0f
#define CONTACT_W  0.5f
#define HCP_W      1.0f
#define POSE_W     0.01f
#define HANDPOSE_W 0.01f
#define ANGLE_W    0.1f
#define A1c 0.04f
#define A2c 0.04f
#define B1c 0.07f
#define B2c 0.06f
#define C1c 0.01f
#define C2c 0.01f
#define D1c 0.023f
#define D2c 0.02f

#define FBIG 3.402823e38f

__device__ __forceinline__ float waveReduceSum(float x) {
#pragma unroll
    for (int o = 32; o > 0; o >>= 1) x += __shfl_down(x, o, 64);
    return x;
}
__device__ __forceinline__ float waveReduceMin(float x) {
#pragma unroll
    for (int o = 32; o > 0; o >>= 1) x = fminf(x, __shfl_down(x, o, 64));
    return x;
}

// inside[v] without a scatter array: ds is sorted & duplicate-free.
__device__ __forceinline__ bool is_inside(int v, const int* __restrict__ ds,
                                          const int* __restrict__ ext, int NDS) {
    int lo = 0, hi = NDS - 1;
    while (lo <= hi) {
        int mid = (lo + hi) >> 1;
        int dv = ds[mid];
        if (dv == v) return ext[mid] == 0;
        if (dv < v) lo = mid + 1; else hi = mid - 1;
    }
    return false;
}

// accum slots (floats):
// 0: lout_sum 1: lout_cnt 2: rout_sum 3: rout_cnt
// 4: lin_sum  5: lin_cnt  6: rin_sum  7: rin_cnt
// 8: close_cnt
// 9,10,11: nbar_sum xyz
// 12,13,14: S xyz  (S = sum over close verts of normalized vn[idx])

// K1: gdi[v] = min_j geodist[v, ivc[j]]. Plain store, zero atomics.
__global__ __launch_bounds__(256) void k_gdi(
    const float* __restrict__ geodist, const int* __restrict__ ivc,
    float* __restrict__ gdi, int NV, int NC)
{
    __shared__ int sivc[512];
    int v = blockIdx.x;
    const float* row = geodist + (size_t)v * (size_t)NV;
    for (int j = threadIdx.x; j < NC && j < 512; j += 256) sivc[j] = ivc[j];
    __syncthreads();
    float m = FBIG;
    for (int j = threadIdx.x; j < NC; j += 256) {
        int c = (j < 512) ? sivc[j] : ivc[j];
        m = fminf(m, row[c]);
    }
    m = waveReduceMin(m);
    __shared__ float sm[4];
    int lane = threadIdx.x & 63;
    int w = threadIdx.x >> 6;
    if (lane == 0) sm[w] = m;
    __syncthreads();
    if (threadIdx.x == 0)
        gdi[v] = fminf(fminf(sm[0], sm[1]), fminf(sm[2], sm[3]));
}

// K2: face-normal scatter-add; close histogram m[idx]; hand-contact terms.
__global__ __launch_bounds__(256) void k_scatter(
    const float* __restrict__ verts, const int* __restrict__ faces,
    float* __restrict__ vn,
    const float* __restrict__ v2v_min, const int* __restrict__ v2v_min_idx,
    float* __restrict__ mf,
    const int* __restrict__ ds, const int* __restrict__ exterior,
    const int* __restrict__ hcp, const float* __restrict__ hcpw,
    float* __restrict__ accum,
    int NF, int NV, int NDS, int HA)
{
    int t = blockIdx.x * blockDim.x + threadIdx.x;
    // face normals
    if (t < NF) {
        int i0 = faces[t * 3 + 0];
        int i1 = faces[t * 3 + 1];
        int i2 = faces[t * 3 + 2];
        float p0x = verts[i0 * 3 + 0], p0y = verts[i0 * 3 + 1], p0z = verts[i0 * 3 + 2];
        float ax = verts[i1 * 3 + 0] - p0x;
        float ay = verts[i1 * 3 + 1] - p0y;
        float az = verts[i1 * 3 + 2] - p0z;
        float bx = verts[i2 * 3 + 0] - p0x;
        float by = verts[i2 * 3 + 1] - p0y;
        float bz = verts[i2 * 3 + 2] - p0z;
        float nx = ay * bz - az * by;
        float ny = az * bx - ax * bz;
        float nz = ax * by - ay * bx;
        atomicAdd(&vn[i0 * 3 + 0], nx);
        atomicAdd(&vn[i0 * 3 + 1], ny);
        atomicAdd(&vn[i0 * 3 + 2], nz);
        atomicAdd(&vn[i1 * 3 + 0], nx);
        atomicAdd(&vn[i1 * 3 + 1], ny);
        atomicAdd(&vn[i1 * 3 + 2], nz);
        atomicAdd(&vn[i2 * 3 + 0], nx);
        atomicAdd(&vn[i2 * 3 + 1], ny);
        atomicAdd(&vn[i2 * 3 + 2], nz);
    }
    float a[9];
#pragma unroll
    for (int k = 0; k < 9; ++k) a[k] = 0.f;
    // close histogram (multiplicity of v2v_min_idx over close vertices)
    if (t < NV) {
        if (v2v_min[t] < 0.01f) {
            atomicAdd(&mf[v2v_min_idx[t]], 1.0f);
            a[8] += 1.0f;  // close_cnt
        }
    }
    // hand contact terms (inside via binary search on sorted ds)
    if (t < HA) {
        int li = hcp[t];
        int ri = hcp[HA + t];
        float lw = 1.0f - 0.1f * hcpw[t];
        float rw = 1.0f - 0.1f * hcpw[HA + t];
        float lvm = v2v_min[li];
        float rvm = v2v_min[ri];
        if (is_inside(li, ds, exterior, NDS)) {
            a[4] += D1c * tanhf(lvm / D2c);      // lin_sum
            a[5] += 1.0f;
        } else {
            a[0] += lw * C1c * tanhf(lvm / C2c); // lout_sum
            a[1] += 1.0f;
        }
        if (is_inside(ri, ds, exterior, NDS)) {
            a[6] += D1c * tanhf(rvm / D2c);      // rin_sum
            a[7] += 1.0f;
        } else {
            a[2] += rw * C1c * tanhf(rvm / C2c); // rout_sum
            a[3] += 1.0f;
        }
    }
#pragma unroll
    for (int k = 0; k < 9; ++k) a[k] = waveReduceSum(a[k]);
    __shared__ float s[4][9];
    int lane = threadIdx.x & 63;
    int w = threadIdx.x >> 6;
    if (lane == 0) {
#pragma unroll
        for (int k = 0; k < 9; ++k) s[w][k] = a[k];
    }
    __syncthreads();
    if (threadIdx.x < 9) {
        float v = s[0][threadIdx.x] + s[1][threadIdx.x] + s[2][threadIdx.x] + s[3][threadIdx.x];
        if (v != 0.f) atomicAdd(&accum[threadIdx.x], v);
    }
}

// K3: normalize vn in place; reduce nbar_sum and S = sum m[u]*vn_norm[u].
__global__ __launch_bounds__(256) void k_normalize(
    float* __restrict__ vn, const float* __restrict__ mf,
    float* __restrict__ accum, int NV)
{
    int t = blockIdx.x * blockDim.x + threadIdx.x;
    float a[6] = {0.f, 0.f, 0.f, 0.f, 0.f, 0.f};
    if (t < NV) {
        float x = vn[t * 3 + 0];
        float y = vn[t * 3 + 1];
        float z = vn[t * 3 + 2];
        float inv = 1.0f / (sqrtf(x * x + y * y + z * z) + 1e-12f);
        x *= inv; y *= inv; z *= inv;
        vn[t * 3 + 0] = x;
        vn[t * 3 + 1] = y;
        vn[t * 3 + 2] = z;
        a[0] = x; a[1] = y; a[2] = z;
        float mm = mf[t];
        a[3] = mm * x; a[4] = mm * y; a[5] = mm * z;
    }
#pragma unroll
    for (int k = 0; k < 6; ++k) a[k] = waveReduceSum(a[k]);
    __shared__ float s[4][6];
    int lane = threadIdx.x & 63;
    int w = threadIdx.x >> 6;
    if (lane == 0) {
#pragma unroll
        for (int k = 0; k < 6; ++k) s[w][k] = a[k];
    }
    __syncthreads();
    if (threadIdx.x < 6) {
        float v = s[0][threadIdx.x] + s[1][threadIdx.x] + s[2][threadIdx.x] + s[3][threadIdx.x];
        if (v != 0.f) atomicAdd(&accum[9 + threadIdx.x], v);
    }
}

// K4: single block — outside sum, ds terms, pose sums, final combine.
__global__ __launch_bounds__(1024) void k_final(
    const float* __restrict__ gdi,
    const float* __restrict__ verts, const float* __restrict__ iverts,
    const float* __restrict__ v2v_min,
    const int* __restrict__ ds, const int* __restrict__ exterior,
    const float* __restrict__ bp, const float* __restrict__ ip,
    const float* __restrict__ lh, const float* __restrict__ rh,
    const float* __restrict__ accum,
    float* __restrict__ out, int NV, int NDS)
{
    int tid = threadIdx.x;
    float outside = 0.f, cs = 0.f, cc = 0.f, ins = 0.f, inc = 0.f;
    float pose = 0.f, hand = 0.f;
    for (int t = tid; t < NV; t += 1024) {
        float g = gdi[t];
        float dx = iverts[t * 3 + 0] - verts[t * 3 + 0];
        float dy = iverts[t * 3 + 1] - verts[t * 3 + 1];
        float dz = iverts[t * 3 + 2] - verts[t * 3 + 2];
        float v2v0 = sqrtf(dx * dx + dy * dy + dz * dz);
        outside += v2v0 * 4.0f * g * g;
    }
    for (int j = tid; j < NDS; j += 1024) {
        int d = ds[j];
        float vm = v2v_min[d];
        if (exterior[j]) {
            float wo = 1.0f / (5.0f * gdi[d] + 1.0f);
            cs += A1c * wo * tanhf(vm / A2c);
            cc += 1.0f;
        } else {
            ins += B1c * tanhf(vm / B2c);
            inc += 1.0f;
        }
    }
    if (tid < 63) {
        float d = bp[tid] - ip[tid];
        pose = d * d;
    }
    if (tid < 45) {
        hand = lh[tid] * lh[tid] + rh[tid] * rh[tid];
    }
    float a[7] = {outside, cs, cc, ins, inc, pose, hand};
#pragma unroll
    for (int k = 0; k < 7; ++k) a[k] = waveReduceSum(a[k]);
    __shared__ float s[16][7];
    int lane = tid & 63;
    int w = tid >> 6;
    if (lane == 0) {
#pragma unroll
        for (int k = 0; k < 7; ++k) s[w][k] = a[k];
    }
    __syncthreads();
    if (tid == 0) {
        float r[7];
#pragma unroll
        for (int k = 0; k < 7; ++k) {
            float v = 0.f;
#pragma unroll
            for (int ww = 0; ww < 16; ++ww) v += s[ww][k];
            r[k] = v;
        }
        float lout_s = accum[0], lout_c = accum[1];
        float rout_s = accum[2], rout_c = accum[3];
        float lin_s  = accum[4], lin_c  = accum[5];
        float rin_s  = accum[6], rin_c  = accum[7];
        float close_c = accum[8];
        float nbx = accum[9]  / (float)NV;
        float nby = accum[10] / (float)NV;
        float nbz = accum[11] / (float)NV;
        float Sdot = accum[12] * nbx + accum[13] * nby + accum[14] * nbz;

        float contactloss = CONTACT_W * (r[2] > 0.f ? r[1] / r[2] : 0.f);
        float insideloss  = INSIDE_W  * (r[4] > 0.f ? r[3] / r[4] : 0.f);
        float hc_out = (lout_c > 0.f ? lout_s / lout_c : 0.f) + (rout_c > 0.f ? rout_s / rout_c : 0.f);
        float hc_in  = (lin_c  > 0.f ? lin_s  / lin_c  : 0.f) + (rin_c  > 0.f ? rin_s  / rin_c  : 0.f);
        float hand_contact_loss = HCP_W * (hc_in + hc_out);
        // masked_mean(1 + vn[idx].nbar, close) = (close_c + S.nbar) / close_c
        float angle_loss = ANGLE_W * (close_c > 0.f ? (close_c + Sdot) / close_c : 0.f);
        float outsideloss = OUTSIDE_W * r[0];
        float pose_prior_loss = POSE_W * r[5];
        float hand_pose_prior_loss = HANDPOSE_W * r[6];
        out[0] = contactloss + insideloss + outsideloss + pose_prior_loss +
                 hand_pose_prior_loss + angle_loss + hand_contact_loss;
    }
}

extern "C" void kernel_launch(void* const* d_in, const int* in_sizes, int n_in,
                              void* d_out, int out_size, void* d_ws, size_t ws_size,
                              hipStream_t stream)
{
    const float* verts    = (const float*)d_in[0];
    const float* v2v_min  = (const float*)d_in[1];
    const float* geodist  = (const float*)d_in[2];
    const float* hcpw     = (const float*)d_in[3];
    const float* bp       = (const float*)d_in[4];
    const float* ip       = (const float*)d_in[5];
    const float* lh       = (const float*)d_in[6];
    const float* rh       = (const float*)d_in[7];
    const float* iverts   = (const float*)d_in[8];
    const int*   vmi      = (const int*)d_in[9];
    const int*   exterior = (const int*)d_in[10];
    const int*   ds       = (const int*)d_in[11];
    const int*   ivc      = (const int*)d_in[12];
    const int*   hcp      = (const int*)d_in[13];
    const int*   faces    = (const int*)d_in[14];

    int NV  = in_sizes[1];
    int NDS = in_sizes[11];
    int NC  = in_sizes[12];
    int HA  = in_sizes[13] / 2;
    int NF  = in_sizes[14] / 3;

    float* accum = (float*)d_ws;                  // 32 floats
    float* vn    = accum + 32;                    // 3*NV floats
    float* mf    = vn + 3 * (size_t)NV;           // NV floats (close-idx histogram)
    float* gdi   = mf + NV;                       // NV floats (plain-stored, no init)

    size_t zbytes = (size_t)(32 + 4 * (size_t)NV) * sizeof(float); // accum+vn+mf
    hipMemsetAsync(d_ws, 0, zbytes, stream);

    // K1: independent of K2/K3 (serialized on stream; no atomics at all).
    k_gdi<<<NV, 256, 0, stream>>>(geodist, ivc, gdi, NV, NC);

    int nmax = NF > NV ? NF : NV;
    k_scatter<<<(nmax + 255) / 256, 256, 0, stream>>>(
        verts, faces, vn, v2v_min, vmi, mf, ds, exterior, hcp, hcpw, accum,
        NF, NV, NDS, HA);

    k_normalize<<<(NV + 255) / 256, 256, 0, stream>>>(vn, mf, accum, NV);

    k_final<<<1, 1024, 0, stream>>>(gdi, verts, iverts, v2v_min, ds, exterior,
                                    bp, ip, lh, rh, accum, (float*)d_out, NV, NDS);
}